// Round 10
// baseline (271.417 us; speedup 1.0000x reference)
//
#include <hip/hip_runtime.h>

typedef _Float16 half8 __attribute__((ext_vector_type(8)));
typedef _Float16 half4 __attribute__((ext_vector_type(4)));
typedef float f32x4 __attribute__((ext_vector_type(4)));
typedef float f32x16 __attribute__((ext_vector_type(16)));
typedef int int4v __attribute__((ext_vector_type(4)));

#define ROWS 32
#define HP 136                 // h row pitch (halfs): 128 + 8 pad
#define HB (ROWS * HP)
#define LOG2E 1.442695041f
#define MFMA32(a,b,c) __builtin_amdgcn_mfma_f32_32x32x16_f16((a),(b),(c),0,0,0)
#define MFMA16(a,b,c) __builtin_amdgcn_mfma_f32_16x16x32_f16((a),(b),(c),0,0,0)

__global__ __launch_bounds__(256, 2)
void traj_gru(const float* __restrict__ history,
              const float* __restrict__ w_ih, const float* __restrict__ w_hh,
              const float* __restrict__ b_ih, const float* __restrict__ b_hh,
              const float* __restrict__ w1, const float* __restrict__ b1,
              const float* __restrict__ w2, const float* __restrict__ b2,
              float* __restrict__ out)
{
    __shared__ __align__(16) _Float16 hbuf[2 * HB];          // 17,408 B ping-pong h [batch][dim]
    __shared__ __align__(16) _Float16 xhist[50 * ROWS * 6];  // 19,200 B [t][batch][6]
    __shared__ __align__(16) _Float16 xdec[ROWS * 8];        //    512 B
    __shared__ __align__(16) _Float16 w2f[4 * 4 * 16 * 8];   //  4,096 B  => 41,216 total

    const int tid  = threadIdx.x;
    const int wave = tid >> 6;            // 0..3 = m-tile (dims 32*wave..+31)
    const int lane = tid & 63;
    const int l31  = lane & 31;
    const int q2   = lane >> 5;
    const int ln16 = lane & 15;           // head phase2
    const int q    = lane >> 4;
    const int rowbase = blockIdx.x * ROWS;
    const int dim0 = wave * 32 + l31;     // this lane's A-frag dim (gru & head p1)

    // ---- init LDS ----
    for (int i = tid; i < 2 * HB; i += 256) hbuf[i] = (_Float16)0;
    for (int i = tid; i < ROWS * 8; i += 256) xdec[i] = (_Float16)0;
    for (int i = tid; i < 4 * 4 * 16 * 8; i += 256) w2f[i] = (_Float16)0;
    __syncthreads();
    for (int idx = tid; idx < ROWS * 300; idx += 256) {
        int r = idx / 300, rem = idx - r * 300;
        int t = rem / 6, c = rem - t * 6;
        xhist[(t * ROWS + r) * 6 + c] = (_Float16)history[(rowbase + r) * 300 + rem];
    }
    if (tid < ROWS) { xdec[tid * 8 + 6] = (_Float16)1.0f; xdec[tid * 8 + 7] = (_Float16)1.0f; }
    for (int idx = tid; idx < 6 * 128; idx += 256) {  // w2 -> 16x16 B-frag table (round-9 verified)
        int n = idx >> 7, k = idx & 127;
        int kt = k >> 5, qq = (k >> 3) & 3, j = k & 7;
        w2f[((kt * 4 + qq) * 16 + n) * 8 + j] = (_Float16)w2[n * 128 + k];
    }

    // ---- persistent gru weight A-frags: m=l31 -> dim0, k = 16*kt + 8*q2 + j ----
    // r,z scaled by -log2e; n by -2log2e
    half8 Wg[3][8];
    #pragma unroll
    for (int g = 0; g < 3; ++g) {
        float sc = (g < 2) ? -LOG2E : -2.0f * LOG2E;
        #pragma unroll
        for (int kt = 0; kt < 8; ++kt) {
            const float* p = w_hh + (g * 128 + dim0) * 128 + kt * 16 + q2 * 8;
            half8 v;
            #pragma unroll
            for (int j = 0; j < 8; ++j) v[j] = (_Float16)(p[j] * sc);
            Wg[g][kt] = v;
        }
    }
    // x A-frags: k(=j, q2==0 half) <6 = w_ih; j==6 = bias (combined) — acc init stays 0
    half8 Wx[3];
    #pragma unroll
    for (int g = 0; g < 3; ++g) {
        float sc = (g < 2) ? -LOG2E : -2.0f * LOG2E;
        half8 v = {0,0,0,0,0,0,0,0};
        if (q2 == 0) {
            #pragma unroll
            for (int j = 0; j < 6; ++j) v[j] = (_Float16)(w_ih[(g * 128 + dim0) * 6 + j] * sc);
            float b = (g == 0) ? (b_ih[dim0] + b_hh[dim0])
                    : (g == 1) ? (b_ih[128 + dim0] + b_hh[128 + dim0])
                               : b_ih[256 + dim0];
            v[6] = (_Float16)(b * sc);
        }
        Wx[g] = v;
    }
    half8 Wbh = {0,0,0,0,0,0,0,0};        // k==7 -> b_hh n-gate bias, lands in ahh
    if (q2 == 0) Wbh[7] = (_Float16)(b_hh[256 + dim0] * (-2.0f * LOG2E));

    const float b2r = (ln16 < 6) ? b2[ln16] : 0.0f;

    float hp[16] = {};   // h_prev, C-layout: batch=l31, dim = 32*wave + (r&3)+8*(r>>2)+4*q2

    __syncthreads();

    // ---- anti-phase stagger for the 2 co-resident blocks (perf-only) ----
    {
        int ph = blockIdx.x & 3;
        for (int i = 0; i < ph; ++i) __builtin_amdgcn_s_sleep(13);  // ~832 cyc each
    }

    auto gru_step = [&](int p, int t, bool enc) {
        const _Float16* hb = hbuf + p * HB;
        _Float16*       hn = hbuf + (p ^ 1) * HB;

        half8 Bx;
        if (enc) {
            int4v d = {0, 0, 0, 0};
            if (q2 == 0) {
                const int* xi = (const int*)xhist;
                int base = (t * ROWS + l31) * 3;
                d[0] = xi[base]; d[1] = xi[base + 1]; d[2] = xi[base + 2];
                d[3] = 0x3C003C00;                    // k6 = 1.0 (bias), k7 = 1.0 (bhn)
            }
            Bx = __builtin_bit_cast(half8, d);
        } else {
            half8 z = {0,0,0,0,0,0,0,0};
            Bx = (q2 == 0) ? *(const half8*)(xdec + l31 * 8) : z;
        }

        f32x16 ar = {0,0,0,0,0,0,0,0,0,0,0,0,0,0,0,0};
        f32x16 az = ar, ah = ar, an = ar;
        const _Float16* rp = hb + l31 * HP + q2 * 8;

        half8 Bf[4];
        #pragma unroll
        for (int kt = 0; kt < 4; ++kt) Bf[kt] = *(const half8*)(rp + kt * 16);
        #pragma unroll
        for (int kt = 0; kt < 4; ++kt) {
            ar = MFMA32(Wg[0][kt], Bf[kt], ar);
            az = MFMA32(Wg[1][kt], Bf[kt], az);
            ah = MFMA32(Wg[2][kt], Bf[kt], ah);
        }
        #pragma unroll
        for (int kt = 0; kt < 4; ++kt) Bf[kt] = *(const half8*)(rp + (kt + 4) * 16);
        #pragma unroll
        for (int kt = 0; kt < 4; ++kt) {
            ar = MFMA32(Wg[0][kt + 4], Bf[kt], ar);
            az = MFMA32(Wg[1][kt + 4], Bf[kt], az);
            ah = MFMA32(Wg[2][kt + 4], Bf[kt], ah);
        }
        ar = MFMA32(Wx[0], Bx, ar);
        az = MFMA32(Wx[1], Bx, az);
        an = MFMA32(Wx[2], Bx, an);
        ah = MFMA32(Wbh, Bx, ah);

        #pragma unroll
        for (int rq = 0; rq < 4; ++rq) {
            half4 hv;
            #pragma unroll
            for (int i = 0; i < 4; ++i) {
                int ri = rq * 4 + i;
                float er = __builtin_amdgcn_exp2f(ar[ri]);
                float r  = __builtin_amdgcn_rcpf(1.0f + er);
                float tt = __builtin_fmaf(r, ah[ri], an[ri]);
                float et = __builtin_amdgcn_exp2f(tt);
                float ez = __builtin_amdgcn_exp2f(az[ri]);
                float d1 = 1.0f + et;
                float rd = __builtin_amdgcn_rcpf(d1 * (1.0f + ez));
                float t1 = __builtin_fmaf(-et, ez, ez);          // (1-et)*ez
                float nm = __builtin_fmaf(hp[ri], d1, t1);
                float h  = nm * rd;
                hp[ri] = h;
                hv[i] = (_Float16)h;
            }
            *(half4*)(hn + l31 * HP + wave * 32 + rq * 8 + q2 * 4) = hv;
        }
        __syncthreads();
    };

    auto head_step = [&](int f, int p) {
        const _Float16* hb = hbuf + p * HB;
        _Float16*       a1 = hbuf + (p ^ 1) * HB;     // dead ping-pong half

        // re-materialize w1 frags from global (L2-hot); issue all loads first
        f32x4 wr[16];
        const f32x4* pw4 = (const f32x4*)(w1 + dim0 * 128);
        #pragma unroll
        for (int kt = 0; kt < 8; ++kt) {
            wr[2 * kt]     = pw4[kt * 4 + q2 * 2];
            wr[2 * kt + 1] = pw4[kt * 4 + q2 * 2 + 1];
        }
        const _Float16* rp = hb + l31 * HP + q2 * 8;
        f32x16 a = {0,0,0,0,0,0,0,0,0,0,0,0,0,0,0,0};
        #pragma unroll
        for (int kt = 0; kt < 8; ++kt) {
            half8 wv;
            #pragma unroll
            for (int j = 0; j < 4; ++j) { wv[j] = (_Float16)wr[2*kt][j]; wv[4+j] = (_Float16)wr[2*kt+1][j]; }
            half8 bf = *(const half8*)(rp + kt * 16);
            a = MFMA32(wv, bf, a);
        }
        {   // + b1 via bias MFMA (k==0 lane)
            half8 bx1 = {0,0,0,0,0,0,0,0}, wb = {0,0,0,0,0,0,0,0};
            if (q2 == 0) { bx1[0] = (_Float16)1.0f; wb[0] = (_Float16)b1[dim0]; }
            a = MFMA32(wb, bx1, a);
        }
        #pragma unroll
        for (int rq = 0; rq < 4; ++rq) {
            half4 v;
            #pragma unroll
            for (int i = 0; i < 4; ++i) {
                float x = a[rq * 4 + i];
                v[i] = (_Float16)(x > 0.0f ? x : 0.0f);
            }
            *(half4*)(a1 + l31 * HP + wave * 32 + rq * 8 + q2 * 4) = v;
        }
        __syncthreads();
        if (wave < 2) {   // phase2: 16x16x32, plain a1 read (round-9 verified structure)
            const _Float16* ap = a1 + (wave * 16 + ln16) * HP;
            f32x4 o = {0,0,0,0};
            #pragma unroll
            for (int kt = 0; kt < 4; ++kt) {
                half8 Aa = *(const half8*)(ap + kt * 32 + q * 8);
                half8 Bw = *(const half8*)&w2f[((kt * 4 + q) * 16 + ln16) * 8];
                o = MFMA16(Aa, Bw, o);
            }
            if (ln16 < 6) {
                #pragma unroll
                for (int i = 0; i < 4; ++i) {
                    int row = wave * 16 + q * 4 + i;
                    float v = o[i] + b2r;
                    out[(rowbase + row) * 180 + f * 6 + ln16] = v;
                    xdec[row * 8 + ln16] = (_Float16)v;   // next decoder x (slots 0..5)
                }
            }
        }
        __syncthreads();
    };

    int p = 0;
    #pragma unroll 1
    for (int t = 0; t < 50; ++t) { gru_step(p, t, true); p ^= 1; }
    #pragma unroll 1
    for (int f = 0; f < 30; ++f) {
        gru_step(p, f == 0 ? 49 : 0, f == 0);   // f=0: x = history[:,49]
        p ^= 1;
        head_step(f, p);
    }
}

extern "C" void kernel_launch(void* const* d_in, const int* in_sizes, int n_in,
                              void* d_out, int out_size, void* d_ws, size_t ws_size,
                              hipStream_t stream) {
    (void)in_sizes; (void)n_in; (void)d_ws; (void)ws_size; (void)out_size;
    traj_gru<<<dim3(16384 / ROWS), dim3(256), 0, stream>>>(
        (const float*)d_in[0], (const float*)d_in[1], (const float*)d_in[2],
        (const float*)d_in[3], (const float*)d_in[4], (const float*)d_in[5],
        (const float*)d_in[6], (const float*)d_in[7], (const float*)d_in[8],
        (float*)d_out);
}